// Round 18
// baseline (260.436 us; speedup 1.0000x reference)
//
#include <hip/hip_runtime.h>
#include <hip/hip_fp16.h>

// ---------------------------------------------------------------------------
// GATLayer reduces to:  z = h @ Wfc.T ;  h_out[v] = mean_{e: dst[e]==v} z[src[e]]
// (entmax over singleton dim == 1; entmax over a constant segment == 1/deg)
//
// Fast path:
//   bucket_count (256-thr, TILE 8192; per-block hists -> d_out scratch)
//   -> scan_buckets -> scan_hists (per-block exact bases)
//   -> bin_scatter (LDS counting-sort per tile, then COALESCED linear write)
//   -> gemm (z fp16) -> bucket_gather (round-13 structure; LDS sort key
//      extended to (ld<<2)|srcQuad so each node's run is walked in ascending
//      src quadrant (3.2MB) -> chip-wide phase-aligned z reads, L2-resident).
// ---------------------------------------------------------------------------

#define WS_ALIGN(x) (((x) + (size_t)255) & ~(size_t)255)
#define BBITS 6
#define BNODES 64             // nodes per bucket
#define CAP 4096              // edges sorted per LDS chunk (gather)
#define NKEY 256              // 64 nodes x 4 src quadrants
#define MAXBUCK 2048
#define TILE 8192             // edges per binning block

__device__ inline unsigned pack_h2(float a, float b) {
    __half2 h = __floats2half2_rn(a, b);
    return *reinterpret_cast<unsigned*>(&h);
}

// ---- per-bucket counts; per-block histogram persisted to global ----
__global__ __launch_bounds__(256) void bucket_count(const int* __restrict__ dst,
                                                    int* __restrict__ bcnt,
                                                    int* __restrict__ hists,
                                                    int E, int nbuck) {
    __shared__ int h[MAXBUCK];
    for (int i = threadIdx.x; i < nbuck; i += 256) h[i] = 0;
    __syncthreads();
    int base = blockIdx.x * TILE;
    for (int k = 0; k < TILE / 256; k++) {
        int e = base + threadIdx.x + k * 256;
        if (e < E) atomicAdd(&h[dst[e] >> BBITS], 1);
    }
    __syncthreads();
    int* hrow = hists + (size_t)blockIdx.x * nbuck;
    for (int i = threadIdx.x; i < nbuck; i += 256) {
        int v = h[i];
        hrow[i] = v;
        if (v) atomicAdd(&bcnt[i], v);
    }
}

// ---- exclusive scan of bucket counts (1 block, 1024 thr, nbuck <= 2048) ----
__global__ __launch_bounds__(1024) void scan_buckets(const int* __restrict__ bcnt,
                                                     int* __restrict__ bases,
                                                     int E, int nbuck) {
    __shared__ int sp[1024];
    int t = threadIdx.x;
    int a = (2 * t < nbuck) ? bcnt[2 * t] : 0;
    int b = (2 * t + 1 < nbuck) ? bcnt[2 * t + 1] : 0;
    sp[t] = a + b;
    __syncthreads();
    for (int off = 1; off < 1024; off <<= 1) {
        int x = (t >= off) ? sp[t - off] : 0;
        __syncthreads();
        sp[t] += x;
        __syncthreads();
    }
    int ex = sp[t] - (a + b);     // exclusive base for element 2t
    if (2 * t < nbuck)     bases[2 * t] = ex;
    if (2 * t + 1 < nbuck) bases[2 * t + 1] = ex + a;
    if (t == 0) bases[nbuck] = E;
}

// ---- hists[k][b] := bases[b] + sum_{j<k} hist[j][b]  (column scan, 8-deep) ----
__global__ __launch_bounds__(256) void scan_hists(int* __restrict__ hists,
                                                  const int* __restrict__ bases,
                                                  int nblk, int nbuck) {
    int b = blockIdx.x * 256 + threadIdx.x;
    if (b >= nbuck) return;
    int run = bases[b];
    int k = 0;
    for (; k + 8 <= nblk; k += 8) {
        int v[8];
        size_t i0 = (size_t)k * nbuck + b;
#pragma unroll
        for (int j = 0; j < 8; j++) v[j] = hists[i0 + (size_t)j * nbuck];
#pragma unroll
        for (int j = 0; j < 8; j++) {
            hists[i0 + (size_t)j * nbuck] = run;
            run += v[j];
        }
    }
    for (; k < nblk; k++) {
        size_t i = (size_t)k * nbuck + b;
        int v = hists[i];
        hists[i] = run; run += v;
    }
}

// ---- bin: LDS counting-sort the tile, then coalesced linear write-out ----
__global__ __launch_bounds__(256) void bin_scatter(const int* __restrict__ src,
                                                   const int* __restrict__ dst,
                                                   const int* __restrict__ hists,
                                                   unsigned* __restrict__ binned,
                                                   int E, int nbuck) {
    __shared__ unsigned sed[TILE];            // 32 KB sorted packed edges
    __shared__ unsigned short sbuck[TILE];    // 16 KB bucket id per slot
    __shared__ int lofs[MAXBUCK];             // local exclusive offsets
    __shared__ int lcur[MAXBUCK];             // cursors
    __shared__ int gb[MAXBUCK];               // global bases for this block
    __shared__ int wsum[4];

    int tid = threadIdx.x;
    const int* hrow = hists + (size_t)blockIdx.x * nbuck;
    for (int i = tid; i < nbuck; i += 256) {
        lofs[i] = 0;
        gb[i] = hrow[i];
    }
    __syncthreads();
    int base = blockIdx.x * TILE;
    int lim = E - base;
    if (lim > TILE) lim = TILE;
    // 1) local histogram
    for (int k = 0; k < TILE / 256; k++) {
        int i = tid + k * 256;
        if (i < lim) atomicAdd(&lofs[dst[base + i] >> BBITS], 1);
    }
    __syncthreads();
    // 2) exclusive scan of lofs (8 entries/thread + wave scan + carry)
    {
        int v[8];
        int i0 = tid * 8;
        int s = 0;
#pragma unroll
        for (int j = 0; j < 8; j++) {
            int i = i0 + j;
            v[j] = (i < nbuck) ? lofs[i] : 0;
            s += v[j];
        }
        int lane = tid & 63, wid = tid >> 6;
        int inc = s;
#pragma unroll
        for (int off = 1; off < 64; off <<= 1) {
            int x = __shfl_up(inc, off);
            if (lane >= off) inc += x;
        }
        if (lane == 63) wsum[wid] = inc;
        __syncthreads();
        int carry = 0;
        for (int j = 0; j < wid; j++) carry += wsum[j];
        int run = inc - s + carry;
#pragma unroll
        for (int j = 0; j < 8; j++) {
            int i = i0 + j;
            if (i < nbuck) { lofs[i] = run; lcur[i] = run; }
            run += v[j];
        }
    }
    __syncthreads();
    // 3) place into LDS (sorted by bucket)
    for (int k = 0; k < TILE / 256; k++) {
        int i = tid + k * 256;
        if (i < lim) {
            int d = dst[base + i];
            int b = d >> BBITS;
            int pos = atomicAdd(&lcur[b], 1);
            sed[pos] = ((unsigned)(d & (BNODES - 1)) << 17) |
                       (unsigned)src[base + i];
            sbuck[pos] = (unsigned short)b;
        }
    }
    __syncthreads();
    // 4) coalesced write-out
    for (int k = 0; k < TILE / 256; k++) {
        int i = tid + k * 256;
        if (i < lim) {
            int b = sbuck[i];
            binned[gb[b] + (i - lofs[b])] = sed[i];
        }
    }
}

// ---- z = h @ W.T, fp16 out. W (32 KB) in LDS, broadcast reads. ----
__global__ __launch_bounds__(256) void gemm_z(const float* __restrict__ h,
                                              const float* __restrict__ W,
                                              __half* __restrict__ z, int N) {
    __shared__ float Wl[64 * 128];
    for (int j = threadIdx.x; j < 2048; j += 256) {
        reinterpret_cast<float4*>(Wl)[j] = reinterpret_cast<const float4*>(W)[j];
    }
    __syncthreads();
    int row = blockIdx.x * 256 + threadIdx.x;
    if (row >= N) return;
    float acc[64];
#pragma unroll
    for (int c = 0; c < 64; c++) acc[c] = 0.f;
    const float4* hr = reinterpret_cast<const float4*>(&h[(size_t)row * 128]);
    for (int kv = 0; kv < 32; kv++) {
        float4 hv = hr[kv];
#pragma unroll
        for (int c = 0; c < 64; c++) {
            float4 wv = *reinterpret_cast<const float4*>(&Wl[c * 128 + kv * 4]);
            acc[c] += hv.x * wv.x + hv.y * wv.y + hv.z * wv.z + hv.w * wv.w;
        }
    }
    uint4* zr = reinterpret_cast<uint4*>(&z[(size_t)row * 64]);
#pragma unroll
    for (int c = 0; c < 8; c++) {
        uint4 pk;
        pk.x = pack_h2(acc[8 * c + 0], acc[8 * c + 1]);
        pk.y = pack_h2(acc[8 * c + 2], acc[8 * c + 3]);
        pk.z = pack_h2(acc[8 * c + 4], acc[8 * c + 5]);
        pk.w = pack_h2(acc[8 * c + 6], acc[8 * c + 7]);
        zr[c] = pk;
    }
}

// ---- one 1024-thr (16-wave) block per 64-node bucket. LDS counting sort by
// key (ld<<2 | srcQuad): each node's run walks ascending 3.2MB src quadrant
// -> phase-aligned z reads. Gather inner loop IDENTICAL to round-13 (proven).
__global__ __launch_bounds__(1024, 8) void bucket_gather(
        const unsigned* __restrict__ binned,
        const int* __restrict__ bases,
        const __half* __restrict__ z,
        float* __restrict__ out, int N) {
    __shared__ unsigned sed[CAP];       // srcs sorted by (ld,quad) (16 KB)
    __shared__ int hist[NKEY];
    __shared__ int ioff[NKEY];          // inclusive offsets (chunk)
    __shared__ int eoff[NKEY];          // exclusive offsets (chunk)
    __shared__ int curs[NKEY];
    __shared__ int wsum[4];
    __shared__ int degl[BNODES];        // total degree across chunks

    int b = blockIdx.x;
    int s0 = bases[b], s1 = bases[b + 1];
    int tid = threadIdx.x;
    int wid = tid >> 6, lane = tid & 63;

    if (tid < BNODES) degl[tid] = 0;

    float acc[4];
#pragma unroll
    for (int s = 0; s < 4; s++) acc[s] = 0.f;

    for (int c0 = s0; c0 < s1; c0 += CAP) {
        int cnt = s1 - c0;
        if (cnt > CAP) cnt = CAP;
        if (tid < NKEY) hist[tid] = 0;
        __syncthreads();
        for (int i = tid; i < cnt; i += 1024) {
            unsigned p = binned[c0 + i];
            int key = (int)(((p >> 17) & (BNODES - 1)) << 2) |
                      (int)((p & 0x1FFFFu) >> 15);
            atomicAdd(&hist[key], 1);
        }
        __syncthreads();
        // 256-entry exclusive scan: 4-wave shfl scan + carry
        {
            int v = (tid < NKEY) ? hist[tid] : 0;
            int inc = v;
#pragma unroll
            for (int off = 1; off < 64; off <<= 1) {
                int x = __shfl_up(inc, off);
                if (lane >= off) inc += x;
            }
            if (tid < NKEY && lane == 63) wsum[wid] = inc;
            __syncthreads();
            if (tid < NKEY) {
                int carry = 0;
                for (int j = 0; j < wid; j++) carry += wsum[j];
                inc += carry;
                ioff[tid] = inc;
                eoff[tid] = inc - v;
                curs[tid] = inc - v;
            }
        }
        __syncthreads();
        if (tid < BNODES)
            degl[tid] += ioff[tid * 4 + 3] - eoff[tid * 4];
        for (int i = tid; i < cnt; i += 1024) {
            unsigned p = binned[c0 + i];
            int key = (int)(((p >> 17) & (BNODES - 1)) << 2) |
                      (int)((p & 0x1FFFFu) >> 15);
            int pos = atomicAdd(&curs[key], 1);
            sed[pos] = p & 0x1FFFFu;
        }
        __syncthreads();
#pragma unroll
        for (int s = 0; s < 4; s++) {
            int r = wid * 4 + s;
            int e0 = eoff[r * 4], e1 = ioff[r * 4 + 3];
            float f0 = 0.f, f1 = 0.f, f2 = 0.f, f3 = 0.f;
            float f4 = 0.f, f5 = 0.f, f6 = 0.f, f7 = 0.f;
            int e = e0;
            for (; e + 8 <= e1; e += 8) {
                int q0 = sed[e],     q1 = sed[e + 1], q2 = sed[e + 2], q3 = sed[e + 3];
                int q4 = sed[e + 4], q5 = sed[e + 5], q6 = sed[e + 6], q7 = sed[e + 7];
                f0 += __half2float(z[(size_t)q0 * 64 + lane]);
                f1 += __half2float(z[(size_t)q1 * 64 + lane]);
                f2 += __half2float(z[(size_t)q2 * 64 + lane]);
                f3 += __half2float(z[(size_t)q3 * 64 + lane]);
                f4 += __half2float(z[(size_t)q4 * 64 + lane]);
                f5 += __half2float(z[(size_t)q5 * 64 + lane]);
                f6 += __half2float(z[(size_t)q6 * 64 + lane]);
                f7 += __half2float(z[(size_t)q7 * 64 + lane]);
            }
            for (; e < e1; e++)
                f0 += __half2float(z[(size_t)sed[e] * 64 + lane]);
            acc[s] += ((f0 + f1) + (f2 + f3)) + ((f4 + f5) + (f6 + f7));
        }
        __syncthreads();   // protect sed/ioff/eoff before next chunk
    }
    // write out (coalesced 256B per node row)
    int node0 = b << BBITS;
#pragma unroll
    for (int s = 0; s < 4; s++) {
        int node = node0 + wid * 4 + s;
        if (node < N) {
            int d = degl[wid * 4 + s];
            float sc = (d > 0) ? 1.0f / (float)d : 0.f;
            out[(size_t)node * 64 + lane] = acc[s] * sc;
        }
    }
}

// ---- fallback path (small ws / odd shapes): atomic scatter-add ----
__global__ __launch_bounds__(256) void count_deg(const int* __restrict__ dst,
                                                 int* __restrict__ cnt, int E) {
    int e = blockIdx.x * 256 + threadIdx.x;
    if (e < E) atomicAdd(&cnt[dst[e]], 1);
}

__global__ __launch_bounds__(256) void edge_add(const __half* __restrict__ z,
                                                const int* __restrict__ src,
                                                const int* __restrict__ dst,
                                                float* __restrict__ out, int E) {
    int e = blockIdx.x * 4 + (threadIdx.x >> 6);
    int lane = threadIdx.x & 63;
    if (e >= E) return;
    int s = src[e];
    int d = dst[e];
    float v = __half2float(z[(size_t)s * 64 + lane]);
    atomicAdd(&out[(size_t)d * 64 + lane], v);
}

__global__ __launch_bounds__(256) void scale_out(float* __restrict__ out,
                                                 const int* __restrict__ deg, int N) {
    int v = blockIdx.x * 4 + (threadIdx.x >> 6);
    int lane = threadIdx.x & 63;
    if (v >= N) return;
    int d = deg[v];
    if (d > 0) out[(size_t)v * 64 + lane] *= (1.0f / (float)d);
}

extern "C" void kernel_launch(void* const* d_in, const int* in_sizes, int n_in,
                              void* d_out, int out_size, void* d_ws, size_t ws_size,
                              hipStream_t stream) {
    const float* h   = (const float*)d_in[0];
    const int*   src = (const int*)d_in[2];
    const int*   dst = (const int*)d_in[3];
    const float* Wfc = (const float*)d_in[4];
    float*       out = (float*)d_out;

    int N = in_sizes[0] / 128;
    int E = in_sizes[2];
    (void)n_in;

    int nbuck = (N + BNODES - 1) >> BBITS;
    int nwgE  = (E + TILE - 1) / TILE;

    size_t sz_z    = WS_ALIGN((size_t)N * 64 * sizeof(__half));
    size_t sz_bin  = WS_ALIGN((size_t)E * sizeof(unsigned));
    size_t sz_bkt  = WS_ALIGN((size_t)(2 * MAXBUCK + 2) * sizeof(int));
    size_t need_fast = sz_z + sz_bin + sz_bkt;
    size_t need_hists = (size_t)nwgE * nbuck * sizeof(int);   // in d_out scratch

    char*     ws     = (char*)d_ws;
    __half*   z      = (__half*)ws;
    unsigned* binned = (unsigned*)(ws + sz_z);
    int*      bcnt   = (int*)(ws + sz_z + sz_bin);
    int*      bases  = bcnt + MAXBUCK;            // nbuck+1 entries

    // per-block histograms live in d_out scratch (consumed by bin_scatter
    // before bucket_gather overwrites out). Proven-safe pattern (rounds 5-17).
    int* hists = (int*)d_out;

    bool can_fast = (N <= (1 << 17)) && (nbuck <= MAXBUCK) &&
                    (ws_size >= need_fast) &&
                    ((size_t)out_size * sizeof(float) >= need_hists);

    if (can_fast) {
        hipMemsetAsync(bcnt, 0, (size_t)nbuck * sizeof(int), stream);
        bucket_count<<<nwgE, 256, 0, stream>>>(dst, bcnt, hists, E, nbuck);
        scan_buckets<<<1, 1024, 0, stream>>>(bcnt, bases, E, nbuck);
        scan_hists<<<(nbuck + 255) / 256, 256, 0, stream>>>(hists, bases, nwgE, nbuck);
        bin_scatter<<<nwgE, 256, 0, stream>>>(src, dst, hists, binned, E, nbuck);
        gemm_z<<<(N + 255) / 256, 256, 0, stream>>>(h, Wfc, z, N);
        bucket_gather<<<nbuck, 1024, 0, stream>>>(binned, bases, z, out, N);
    } else if (ws_size >= sz_z + WS_ALIGN((size_t)N * sizeof(int))) {
        // atomic scatter-add fallback
        int* deg = (int*)(ws + sz_z);
        hipMemsetAsync(deg, 0, (size_t)N * sizeof(int), stream);
        hipMemsetAsync(out, 0, (size_t)N * 64 * sizeof(float), stream);
        count_deg<<<(E + 255) / 256, 256, 0, stream>>>(dst, deg, E);
        gemm_z<<<(N + 255) / 256, 256, 0, stream>>>(h, Wfc, z, N);
        edge_add<<<(E + 3) / 4, 256, 0, stream>>>(z, src, dst, out, E);
        scale_out<<<(N + 3) / 4, 256, 0, stream>>>(out, deg, N);
    }
}

// Round 19
// 253.127 us; speedup vs baseline: 1.0289x; 1.0289x over previous
//
#include <hip/hip_runtime.h>
#include <hip/hip_fp16.h>

// ---------------------------------------------------------------------------
// GATLayer reduces to:  z = h @ Wfc.T ;  h_out[v] = mean_{e: dst[e]==v} z[src[e]]
// (entmax over singleton dim == 1; entmax over a constant segment == 1/deg)
//
// Fast path (proven best, round 17 = 253.8 us):
//   bucket_count (256-thr, TILE 8192; per-block hists -> d_out scratch)
//   -> scan_buckets -> scan_hists (per-block exact bases)
//   -> bin_scatter (LDS counting-sort per tile, then COALESCED linear write)
//   -> gemm (z fp16) -> bucket_gather (1024-thr/16-wave block per 64-node
//      bucket, 4 nodes/wave, scalar depth-8; fits (1024,8) without spill).
// ---------------------------------------------------------------------------

#define WS_ALIGN(x) (((x) + (size_t)255) & ~(size_t)255)
#define BBITS 6
#define BNODES 64             // nodes per bucket
#define CAP 4096              // edges sorted per LDS chunk (gather)
#define MAXBUCK 2048
#define TILE 8192             // edges per binning block

__device__ inline unsigned pack_h2(float a, float b) {
    __half2 h = __floats2half2_rn(a, b);
    return *reinterpret_cast<unsigned*>(&h);
}

// ---- per-bucket counts; per-block histogram persisted to global ----
__global__ __launch_bounds__(256) void bucket_count(const int* __restrict__ dst,
                                                    int* __restrict__ bcnt,
                                                    int* __restrict__ hists,
                                                    int E, int nbuck) {
    __shared__ int h[MAXBUCK];
    for (int i = threadIdx.x; i < nbuck; i += 256) h[i] = 0;
    __syncthreads();
    int base = blockIdx.x * TILE;
    for (int k = 0; k < TILE / 256; k++) {
        int e = base + threadIdx.x + k * 256;
        if (e < E) atomicAdd(&h[dst[e] >> BBITS], 1);
    }
    __syncthreads();
    int* hrow = hists + (size_t)blockIdx.x * nbuck;
    for (int i = threadIdx.x; i < nbuck; i += 256) {
        int v = h[i];
        hrow[i] = v;
        if (v) atomicAdd(&bcnt[i], v);
    }
}

// ---- exclusive scan of bucket counts (1 block, 1024 thr, nbuck <= 2048) ----
__global__ __launch_bounds__(1024) void scan_buckets(const int* __restrict__ bcnt,
                                                     int* __restrict__ bases,
                                                     int E, int nbuck) {
    __shared__ int sp[1024];
    int t = threadIdx.x;
    int a = (2 * t < nbuck) ? bcnt[2 * t] : 0;
    int b = (2 * t + 1 < nbuck) ? bcnt[2 * t + 1] : 0;
    sp[t] = a + b;
    __syncthreads();
    for (int off = 1; off < 1024; off <<= 1) {
        int x = (t >= off) ? sp[t - off] : 0;
        __syncthreads();
        sp[t] += x;
        __syncthreads();
    }
    int ex = sp[t] - (a + b);     // exclusive base for element 2t
    if (2 * t < nbuck)     bases[2 * t] = ex;
    if (2 * t + 1 < nbuck) bases[2 * t + 1] = ex + a;
    if (t == 0) bases[nbuck] = E;
}

// ---- hists[k][b] := bases[b] + sum_{j<k} hist[j][b]  (column scan, 8-deep) ----
__global__ __launch_bounds__(256) void scan_hists(int* __restrict__ hists,
                                                  const int* __restrict__ bases,
                                                  int nblk, int nbuck) {
    int b = blockIdx.x * 256 + threadIdx.x;
    if (b >= nbuck) return;
    int run = bases[b];
    int k = 0;
    for (; k + 8 <= nblk; k += 8) {
        int v[8];
        size_t i0 = (size_t)k * nbuck + b;
#pragma unroll
        for (int j = 0; j < 8; j++) v[j] = hists[i0 + (size_t)j * nbuck];
#pragma unroll
        for (int j = 0; j < 8; j++) {
            hists[i0 + (size_t)j * nbuck] = run;
            run += v[j];
        }
    }
    for (; k < nblk; k++) {
        size_t i = (size_t)k * nbuck + b;
        int v = hists[i];
        hists[i] = run; run += v;
    }
}

// ---- bin: LDS counting-sort the tile, then coalesced linear write-out ----
__global__ __launch_bounds__(256) void bin_scatter(const int* __restrict__ src,
                                                   const int* __restrict__ dst,
                                                   const int* __restrict__ hists,
                                                   unsigned* __restrict__ binned,
                                                   int E, int nbuck) {
    __shared__ unsigned sed[TILE];            // 32 KB sorted packed edges
    __shared__ unsigned short sbuck[TILE];    // 16 KB bucket id per slot
    __shared__ int lofs[MAXBUCK];             // local exclusive offsets
    __shared__ int lcur[MAXBUCK];             // cursors
    __shared__ int gb[MAXBUCK];               // global bases for this block
    __shared__ int wsum[4];

    int tid = threadIdx.x;
    const int* hrow = hists + (size_t)blockIdx.x * nbuck;
    for (int i = tid; i < nbuck; i += 256) {
        lofs[i] = 0;
        gb[i] = hrow[i];
    }
    __syncthreads();
    int base = blockIdx.x * TILE;
    int lim = E - base;
    if (lim > TILE) lim = TILE;
    // 1) local histogram
    for (int k = 0; k < TILE / 256; k++) {
        int i = tid + k * 256;
        if (i < lim) atomicAdd(&lofs[dst[base + i] >> BBITS], 1);
    }
    __syncthreads();
    // 2) exclusive scan of lofs (8 entries/thread + wave scan + carry)
    {
        int v[8];
        int i0 = tid * 8;
        int s = 0;
#pragma unroll
        for (int j = 0; j < 8; j++) {
            int i = i0 + j;
            v[j] = (i < nbuck) ? lofs[i] : 0;
            s += v[j];
        }
        int lane = tid & 63, wid = tid >> 6;
        int inc = s;
#pragma unroll
        for (int off = 1; off < 64; off <<= 1) {
            int x = __shfl_up(inc, off);
            if (lane >= off) inc += x;
        }
        if (lane == 63) wsum[wid] = inc;
        __syncthreads();
        int carry = 0;
        for (int j = 0; j < wid; j++) carry += wsum[j];
        int run = inc - s + carry;
#pragma unroll
        for (int j = 0; j < 8; j++) {
            int i = i0 + j;
            if (i < nbuck) { lofs[i] = run; lcur[i] = run; }
            run += v[j];
        }
    }
    __syncthreads();
    // 3) place into LDS (sorted by bucket)
    for (int k = 0; k < TILE / 256; k++) {
        int i = tid + k * 256;
        if (i < lim) {
            int d = dst[base + i];
            int b = d >> BBITS;
            int pos = atomicAdd(&lcur[b], 1);
            sed[pos] = ((unsigned)(d & (BNODES - 1)) << 17) |
                       (unsigned)src[base + i];
            sbuck[pos] = (unsigned short)b;
        }
    }
    __syncthreads();
    // 4) coalesced write-out
    for (int k = 0; k < TILE / 256; k++) {
        int i = tid + k * 256;
        if (i < lim) {
            int b = sbuck[i];
            binned[gb[b] + (i - lofs[b])] = sed[i];
        }
    }
}

// ---- z = h @ W.T, fp16 out. W (32 KB) in LDS, broadcast reads. ----
__global__ __launch_bounds__(256) void gemm_z(const float* __restrict__ h,
                                              const float* __restrict__ W,
                                              __half* __restrict__ z, int N) {
    __shared__ float Wl[64 * 128];
    for (int j = threadIdx.x; j < 2048; j += 256) {
        reinterpret_cast<float4*>(Wl)[j] = reinterpret_cast<const float4*>(W)[j];
    }
    __syncthreads();
    int row = blockIdx.x * 256 + threadIdx.x;
    if (row >= N) return;
    float acc[64];
#pragma unroll
    for (int c = 0; c < 64; c++) acc[c] = 0.f;
    const float4* hr = reinterpret_cast<const float4*>(&h[(size_t)row * 128]);
    for (int kv = 0; kv < 32; kv++) {
        float4 hv = hr[kv];
#pragma unroll
        for (int c = 0; c < 64; c++) {
            float4 wv = *reinterpret_cast<const float4*>(&Wl[c * 128 + kv * 4]);
            acc[c] += hv.x * wv.x + hv.y * wv.y + hv.z * wv.z + hv.w * wv.w;
        }
    }
    uint4* zr = reinterpret_cast<uint4*>(&z[(size_t)row * 64]);
#pragma unroll
    for (int c = 0; c < 8; c++) {
        uint4 pk;
        pk.x = pack_h2(acc[8 * c + 0], acc[8 * c + 1]);
        pk.y = pack_h2(acc[8 * c + 2], acc[8 * c + 3]);
        pk.z = pack_h2(acc[8 * c + 4], acc[8 * c + 5]);
        pk.w = pack_h2(acc[8 * c + 6], acc[8 * c + 7]);
        zr[c] = pk;
    }
}

// ---- one 1024-thr (16-wave) block per 64-node bucket: LDS counting sort +
// depth-8 scalar register gather (proven). Wave w owns nodes [w*4, w*4+4);
// lane = out column. Fits (1024,8) without harmful spill.
__global__ __launch_bounds__(1024, 8) void bucket_gather(
        const unsigned* __restrict__ binned,
        const int* __restrict__ bases,
        const __half* __restrict__ z,
        float* __restrict__ out, int N) {
    __shared__ unsigned sed[CAP];       // srcs sorted by local dst (16 KB)
    __shared__ int hist[BNODES];
    __shared__ int ioff[BNODES];        // inclusive offsets (chunk)
    __shared__ int eoff[BNODES];        // exclusive offsets (chunk)
    __shared__ int curs[BNODES];
    __shared__ int degl[BNODES];        // total degree across chunks

    int b = blockIdx.x;
    int s0 = bases[b], s1 = bases[b + 1];
    int tid = threadIdx.x;
    int wid = tid >> 6, lane = tid & 63;

    if (tid < BNODES) degl[tid] = 0;

    float acc[4];
#pragma unroll
    for (int s = 0; s < 4; s++) acc[s] = 0.f;

    for (int c0 = s0; c0 < s1; c0 += CAP) {
        int cnt = s1 - c0;
        if (cnt > CAP) cnt = CAP;
        if (tid < BNODES) hist[tid] = 0;
        __syncthreads();
        for (int i = tid; i < cnt; i += 1024) {
            unsigned p = binned[c0 + i];
            atomicAdd(&hist[(p >> 17) & (BNODES - 1)], 1);
        }
        __syncthreads();
        if (tid < 64) {                 // single-wave shfl scan
            int v = hist[tid];
            int inc = v;
#pragma unroll
            for (int off = 1; off < 64; off <<= 1) {
                int x = __shfl_up(inc, off);
                if (tid >= off) inc += x;
            }
            ioff[tid] = inc;
            eoff[tid] = inc - v;
            curs[tid] = inc - v;
            degl[tid] += v;
        }
        __syncthreads();
        for (int i = tid; i < cnt; i += 1024) {
            unsigned p = binned[c0 + i];
            int ld = (p >> 17) & (BNODES - 1);
            int pos = atomicAdd(&curs[ld], 1);
            sed[pos] = p & 0x1FFFFu;
        }
        __syncthreads();
#pragma unroll
        for (int s = 0; s < 4; s++) {
            int r = wid * 4 + s;
            int e0 = eoff[r], e1 = ioff[r];
            float f0 = 0.f, f1 = 0.f, f2 = 0.f, f3 = 0.f;
            float f4 = 0.f, f5 = 0.f, f6 = 0.f, f7 = 0.f;
            int e = e0;
            for (; e + 8 <= e1; e += 8) {
                int q0 = sed[e],     q1 = sed[e + 1], q2 = sed[e + 2], q3 = sed[e + 3];
                int q4 = sed[e + 4], q5 = sed[e + 5], q6 = sed[e + 6], q7 = sed[e + 7];
                f0 += __half2float(z[(size_t)q0 * 64 + lane]);
                f1 += __half2float(z[(size_t)q1 * 64 + lane]);
                f2 += __half2float(z[(size_t)q2 * 64 + lane]);
                f3 += __half2float(z[(size_t)q3 * 64 + lane]);
                f4 += __half2float(z[(size_t)q4 * 64 + lane]);
                f5 += __half2float(z[(size_t)q5 * 64 + lane]);
                f6 += __half2float(z[(size_t)q6 * 64 + lane]);
                f7 += __half2float(z[(size_t)q7 * 64 + lane]);
            }
            for (; e < e1; e++)
                f0 += __half2float(z[(size_t)sed[e] * 64 + lane]);
            acc[s] += ((f0 + f1) + (f2 + f3)) + ((f4 + f5) + (f6 + f7));
        }
        __syncthreads();   // protect sed/ioff/eoff before next chunk
    }
    // write out (coalesced 256B per node row)
    int node0 = b << BBITS;
#pragma unroll
    for (int s = 0; s < 4; s++) {
        int node = node0 + wid * 4 + s;
        if (node < N) {
            int d = degl[wid * 4 + s];
            float sc = (d > 0) ? 1.0f / (float)d : 0.f;
            out[(size_t)node * 64 + lane] = acc[s] * sc;
        }
    }
}

// ---- fallback path (small ws / odd shapes): atomic scatter-add ----
__global__ __launch_bounds__(256) void count_deg(const int* __restrict__ dst,
                                                 int* __restrict__ cnt, int E) {
    int e = blockIdx.x * 256 + threadIdx.x;
    if (e < E) atomicAdd(&cnt[dst[e]], 1);
}

__global__ __launch_bounds__(256) void edge_add(const __half* __restrict__ z,
                                                const int* __restrict__ src,
                                                const int* __restrict__ dst,
                                                float* __restrict__ out, int E) {
    int e = blockIdx.x * 4 + (threadIdx.x >> 6);
    int lane = threadIdx.x & 63;
    if (e >= E) return;
    int s = src[e];
    int d = dst[e];
    float v = __half2float(z[(size_t)s * 64 + lane]);
    atomicAdd(&out[(size_t)d * 64 + lane], v);
}

__global__ __launch_bounds__(256) void scale_out(float* __restrict__ out,
                                                 const int* __restrict__ deg, int N) {
    int v = blockIdx.x * 4 + (threadIdx.x >> 6);
    int lane = threadIdx.x & 63;
    if (v >= N) return;
    int d = deg[v];
    if (d > 0) out[(size_t)v * 64 + lane] *= (1.0f / (float)d);
}

extern "C" void kernel_launch(void* const* d_in, const int* in_sizes, int n_in,
                              void* d_out, int out_size, void* d_ws, size_t ws_size,
                              hipStream_t stream) {
    const float* h   = (const float*)d_in[0];
    const int*   src = (const int*)d_in[2];
    const int*   dst = (const int*)d_in[3];
    const float* Wfc = (const float*)d_in[4];
    float*       out = (float*)d_out;

    int N = in_sizes[0] / 128;
    int E = in_sizes[2];
    (void)n_in;

    int nbuck = (N + BNODES - 1) >> BBITS;
    int nwgE  = (E + TILE - 1) / TILE;

    size_t sz_z    = WS_ALIGN((size_t)N * 64 * sizeof(__half));
    size_t sz_bin  = WS_ALIGN((size_t)E * sizeof(unsigned));
    size_t sz_bkt  = WS_ALIGN((size_t)(2 * MAXBUCK + 2) * sizeof(int));
    size_t need_fast = sz_z + sz_bin + sz_bkt;
    size_t need_hists = (size_t)nwgE * nbuck * sizeof(int);   // in d_out scratch

    char*     ws     = (char*)d_ws;
    __half*   z      = (__half*)ws;
    unsigned* binned = (unsigned*)(ws + sz_z);
    int*      bcnt   = (int*)(ws + sz_z + sz_bin);
    int*      bases  = bcnt + MAXBUCK;            // nbuck+1 entries

    // per-block histograms live in d_out scratch (consumed by bin_scatter
    // before bucket_gather overwrites out). Proven-safe pattern (rounds 5-17).
    int* hists = (int*)d_out;

    bool can_fast = (N <= (1 << 17)) && (nbuck <= MAXBUCK) &&
                    (ws_size >= need_fast) &&
                    ((size_t)out_size * sizeof(float) >= need_hists);

    if (can_fast) {
        hipMemsetAsync(bcnt, 0, (size_t)nbuck * sizeof(int), stream);
        bucket_count<<<nwgE, 256, 0, stream>>>(dst, bcnt, hists, E, nbuck);
        scan_buckets<<<1, 1024, 0, stream>>>(bcnt, bases, E, nbuck);
        scan_hists<<<(nbuck + 255) / 256, 256, 0, stream>>>(hists, bases, nwgE, nbuck);
        bin_scatter<<<nwgE, 256, 0, stream>>>(src, dst, hists, binned, E, nbuck);
        gemm_z<<<(N + 255) / 256, 256, 0, stream>>>(h, Wfc, z, N);
        bucket_gather<<<nbuck, 1024, 0, stream>>>(binned, bases, z, out, N);
    } else if (ws_size >= sz_z + WS_ALIGN((size_t)N * sizeof(int))) {
        // atomic scatter-add fallback
        int* deg = (int*)(ws + sz_z);
        hipMemsetAsync(deg, 0, (size_t)N * sizeof(int), stream);
        hipMemsetAsync(out, 0, (size_t)N * 64 * sizeof(float), stream);
        count_deg<<<(E + 255) / 256, 256, 0, stream>>>(dst, deg, E);
        gemm_z<<<(N + 255) / 256, 256, 0, stream>>>(h, Wfc, z, N);
        edge_add<<<(E + 3) / 4, 256, 0, stream>>>(z, src, dst, out, E);
        scale_out<<<(N + 3) / 4, 256, 0, stream>>>(out, deg, N);
    }
}